// Round 5
// baseline (565.018 us; speedup 1.0000x reference)
//
#include <hip/hip_runtime.h>
#include <hip/hip_bf16.h>

#define BATCH 16384
#define HDIM  1024
#define K1    2048
#define N1    4096

typedef __attribute__((ext_vector_type(4))) float f32x4;
typedef __attribute__((ext_vector_type(8))) short short8;

__device__ __forceinline__ unsigned short f2bf(float f) {
  union { float f; unsigned u; } v; v.f = f;
  unsigned r = v.u + 0x7FFFu + ((v.u >> 16) & 1u);
  return (unsigned short)(r >> 16);
}
__device__ __forceinline__ float bf2f(unsigned short h) {
  union { unsigned u; float f; } v; v.u = ((unsigned)h) << 16; return v.f;
}
__device__ __forceinline__ float sigmoidf_(float x) {
  return 1.0f / (1.0f + __builtin_amdgcn_exp2f(x * -1.4426950408889634f));
}
__device__ __forceinline__ float tanhf_(float x) {
  float xc = fminf(fmaxf(x, -8.0f), 8.0f);
  float e = __builtin_amdgcn_exp2f(xc * 2.8853900817779268f);
  return (e - 1.0f) / (e + 1.0f);
}
__device__ __forceinline__ void async16(const void* g, void* l) {
  __builtin_amdgcn_global_load_lds((const __attribute__((address_space(1))) void*)g,
                                   (__attribute__((address_space(3))) void*)l, 16, 0, 0);
}

// ---- conversion pass: U = [x|y] bf16 (16384 x 2048) ----
__global__ void k_convU(const float* __restrict__ x, const float* __restrict__ y,
                        unsigned short* __restrict__ U) {
  const int total = BATCH * (HDIM / 4);
  for (int q = blockIdx.x * blockDim.x + threadIdx.x; q < total;
       q += gridDim.x * blockDim.x) {
    int b = q >> 8;
    int c = (q & 255) << 2;
    float4 xv = *(const float4*)(x + (long)b * HDIM + c);
    float4 yv = *(const float4*)(y + (long)b * HDIM + c);
    uint2 xo, yo;
    xo.x = (unsigned)f2bf(xv.x) | ((unsigned)f2bf(xv.y) << 16);
    xo.y = (unsigned)f2bf(xv.z) | ((unsigned)f2bf(xv.w) << 16);
    yo.x = (unsigned)f2bf(yv.x) | ((unsigned)f2bf(yv.y) << 16);
    yo.y = (unsigned)f2bf(yv.z) | ((unsigned)f2bf(yv.w) << 16);
    *(uint2*)(U + (long)b * K1 + c) = xo;
    *(uint2*)(U + (long)b * K1 + HDIM + c) = yo;
  }
}

// ---- conversion pass: permuted Wcat (4096 x 2048) + Wz bf16 ----
__global__ void k_convW(const float* __restrict__ Wih, const float* __restrict__ Whh,
                        const float* __restrict__ Wz,
                        unsigned short* __restrict__ Wcat, unsigned short* __restrict__ Wzb) {
  const int stride = gridDim.x * blockDim.x;
  const int totalW = N1 * (K1 / 4);
  for (int q = blockIdx.x * blockDim.x + threadIdx.x; q < totalW; q += stride) {
    int np = q >> 9;
    int kb = (q & 511) << 2;
    int B = np >> 8, w = (np >> 6) & 3, c = (np >> 4) & 3, i = np & 15;
    int h = B * 64 + w * 16 + i;
    float4 v;
    if (kb < HDIM) {
      int row = (c == 0) ? h : (c == 1) ? (HDIM + h) : (c == 2) ? (3 * HDIM + h) : (2 * HDIM + h);
      v = *(const float4*)(Wih + (long)row * HDIM + kb);
    } else if (c == 3) {
      v = make_float4(0.f, 0.f, 0.f, 0.f);
    } else {
      int row = (c == 0) ? h : (c == 1) ? (HDIM + h) : (2 * HDIM + h);
      v = *(const float4*)(Whh + (long)row * HDIM + (kb - HDIM));
    }
    uint2 o;
    o.x = (unsigned)f2bf(v.x) | ((unsigned)f2bf(v.y) << 16);
    o.y = (unsigned)f2bf(v.z) | ((unsigned)f2bf(v.w) << 16);
    *(uint2*)(Wcat + (long)np * K1 + kb) = o;
  }
  const int totalZ = HDIM * (HDIM / 4);
  for (int q = blockIdx.x * blockDim.x + threadIdx.x; q < totalZ; q += stride) {
    int n = q >> 8;
    int kb = (q & 255) << 2;
    float4 v = *(const float4*)(Wz + (long)n * HDIM + kb);
    uint2 o;
    o.x = (unsigned)f2bf(v.x) | ((unsigned)f2bf(v.y) << 16);
    o.y = (unsigned)f2bf(v.z) | ((unsigned)f2bf(v.w) << 16);
    *(uint2*)(Wzb + (long)n * HDIM + kb) = o;
  }
}

// ---- 256x256 GEMM core with cross-iteration fragment prefetch ----
// BK=32, 4 LDS tile-buffers, staging distance 3, 8 waves (2M x 4N),
// 1 barrier/kt. Per sub-iter j:
//   stage(j+3); s_waitcnt vmcnt(8) lgkmcnt(0); sched_barrier; s_barrier;
//   { issue 12 ds_read of frags(j+1)  [tile j+1 staged: vmcnt guaranteed] }
//   interleaved with 32 MFMA on frags(j) already in registers.
// LDS reads complete UNDER the MFMA cluster (768 < 1242 cyc/CU).
// lgkm(0)-before-barrier keeps overwrite safety: all reads of a buffer
// drain before any wave passes the barrier preceding its re-staging.
#define STAGE_TILE(TT)                                                          \
  do {                                                                          \
    const int b_ = (TT) & 3;                                                    \
    const long ko_ = (long)(TT) * 32;                                           \
    _Pragma("unroll")                                                           \
    for (int hh = 0; hh < 2; ++hh) {                                            \
      async16(gA + ko_ + (long)hh * 128 * KTOT, AsBase + b_ * 16384 + hh * 8192 + t16); \
      async16(gB + ko_ + (long)hh * 128 * KTOT, BsBase + b_ * 16384 + hh * 8192 + t16); \
    }                                                                           \
  } while (0)

#define SUBITER(AFC, BFC, AFN, BFN, KTJ, VMSTR, DO_PREF)                        \
  do {                                                                          \
    asm volatile("s_waitcnt " VMSTR " lgkmcnt(0)" ::: "memory");                \
    __builtin_amdgcn_sched_barrier(0);                                          \
    __builtin_amdgcn_s_barrier();                                               \
    const char* Ab_ = AsBase + (((KTJ) + 1) & 3) * 16384;                       \
    const char* Bb_ = BsBase + (((KTJ) + 1) & 3) * 16384;                       \
    if (DO_PREF) {                                                              \
      _Pragma("unroll") for (int n = 0; n < 4; ++n)                             \
        BFN[n] = *(const short8*)(Bb_ + offB4[n]);                              \
      _Pragma("unroll") for (int m = 0; m < 4; ++m)                             \
        AFN[m] = *(const short8*)(Ab_ + offA[m]);                               \
    }                                                                           \
    __builtin_amdgcn_s_setprio(1);                                              \
    _Pragma("unroll") for (int m = 0; m < 4; ++m)                               \
      _Pragma("unroll") for (int n = 0; n < 4; ++n)                             \
        acc[m][n] = __builtin_amdgcn_mfma_f32_16x16x32_bf16(AFC[m], BFC[n], acc[m][n], 0, 0, 0); \
    __builtin_amdgcn_s_setprio(0);                                              \
    if (DO_PREF) {                                                              \
      _Pragma("unroll") for (int m = 4; m < 8; ++m)                             \
        AFN[m] = *(const short8*)(Ab_ + offA[m]);                               \
    }                                                                           \
    __builtin_amdgcn_s_setprio(1);                                              \
    _Pragma("unroll") for (int m = 4; m < 8; ++m)                               \
      _Pragma("unroll") for (int n = 0; n < 4; ++n)                             \
        acc[m][n] = __builtin_amdgcn_mfma_f32_16x16x32_bf16(AFC[m], BFC[n], acc[m][n], 0, 0, 0); \
    __builtin_amdgcn_s_setprio(0);                                              \
  } while (0)

template <int KTOT>
__device__ __forceinline__ void gemm256(const unsigned short* __restrict__ A,
                                        const unsigned short* __restrict__ B,
                                        long arow0, long brow0,
                                        char* AsBase, char* BsBase,
                                        f32x4 acc[8][4]) {
  const int t = threadIdx.x;
  const int lane = t & 63;
  const int wv = t >> 6;
  const int wm = wv >> 2, wn = wv & 3;
  const int rA = lane & 15;
  const int cphys = (((lane >> 4) << 4)) ^ (((rA >> 1) & 3) << 4);
  const int t16 = t * 16;
  const int s0 = t16 ^ (((t >> 3) & 3) << 4);   // inverse-swizzled source offset
  const int r0 = s0 >> 6, c0 = s0 & 63;
  const unsigned short* gA = A + (arow0 + r0) * (long)KTOT + (c0 >> 1);
  const unsigned short* gB = B + (brow0 + r0) * (long)KTOT + (c0 >> 1);
  const int NT = KTOT / 32;

  // LDS byte offsets (within one 16KB buffer) of this wave's 12 fragments
  int offA[8], offB4[4];
#pragma unroll
  for (int m = 0; m < 8; ++m)
    offA[m] = (wm * 128 + (m >> 2) * 64 + (m & 3) * 16 + rA) * 64 + cphys;
#pragma unroll
  for (int n = 0; n < 4; ++n)
    offB4[n] = (wn * 64 + n * 16 + rA) * 64 + cphys;

  // prologue: stage tiles 0,1,2; read frags(0)
#pragma unroll
  for (int tt = 0; tt < 3; ++tt)
#pragma unroll
    for (int hh = 0; hh < 2; ++hh) {
      async16(gA + tt * 32 + (long)hh * 128 * KTOT, AsBase + tt * 16384 + hh * 8192 + t16);
      async16(gB + tt * 32 + (long)hh * 128 * KTOT, BsBase + tt * 16384 + hh * 8192 + t16);
    }
  asm volatile("s_waitcnt vmcnt(8)" ::: "memory");
  __builtin_amdgcn_s_barrier();

  short8 afA[8], bfA[4], afB[8], bfB[4];
#pragma unroll
  for (int n = 0; n < 4; ++n) bfA[n] = *(const short8*)(BsBase + offB4[n]);
#pragma unroll
  for (int m = 0; m < 8; ++m) afA[m] = *(const short8*)(AsBase + offA[m]);

#pragma unroll 1
  for (int kt = 0; kt < NT - 4; kt += 2) {
    STAGE_TILE(kt + 3);
    SUBITER(afA, bfA, afB, bfB, kt, "vmcnt(8)", true);
    STAGE_TILE(kt + 4);
    SUBITER(afB, bfB, afA, bfA, kt + 1, "vmcnt(8)", true);
  }
  // tail: sub-iters NT-4 .. NT-1 (NT is a multiple of 4 here: 64 or 32)
  STAGE_TILE(NT - 1);
  SUBITER(afA, bfA, afB, bfB, NT - 4, "vmcnt(8)", true);
  SUBITER(afB, bfB, afA, bfA, NT - 3, "vmcnt(4)", true);
  SUBITER(afA, bfA, afB, bfB, NT - 2, "vmcnt(0)", true);
  SUBITER(afB, bfB, afA, bfA, NT - 1, "vmcnt(0)", false);
}

// ---- phase 1: fused U@Wcat^T + LEM elementwise ----
__global__ __launch_bounds__(512, 2) void k_gemm1(
    const unsigned short* __restrict__ U, const unsigned short* __restrict__ Wcat,
    const float* __restrict__ z, const float* __restrict__ dtp,
    const float* __restrict__ bih, const float* __restrict__ bhh,
    const float* __restrict__ Wdt, const float* __restrict__ bdt,
    float* __restrict__ out, unsigned short* __restrict__ znb,
    unsigned short* __restrict__ sbb) {
  __shared__ char As[65536];
  __shared__ char Bs[65536];
  const int bid = blockIdx.x;
  const int sid = (bid & 7) * 128 + (bid >> 3);  // XCD-bijective swizzle (1024 % 8 == 0)
  const int bm = sid >> 4, bn = sid & 15;
  f32x4 acc[8][4];
#pragma unroll
  for (int r = 0; r < 8; ++r)
#pragma unroll
    for (int n = 0; n < 4; ++n) acc[r][n] = (f32x4)(0.0f);

  gemm256<K1>(U, Wcat, (long)bm * 256, (long)bn * 256, As, Bs, acc);

  const int t = threadIdx.x, lane = t & 63, wv = t >> 6;
  const int wm = wv >> 2, wn = wv & 3;
  const int rA = lane & 15, q4 = (lane >> 4) << 2;
  const int h = bn * 64 + wn * 16 + rA;
  const int rowbase = bm * 256 + wm * 128;
  const float bi0 = bih[h] + bhh[h];
  const float bi1 = bih[HDIM + h] + bhh[HDIM + h];
  const float bi2 = bih[3 * HDIM + h] + bhh[2 * HDIM + h];
  const float bi3 = bih[2 * HDIM + h];
  const float wdt0 = Wdt[0], wdt1 = Wdt[1], bdt0 = bdt[0], bdt1 = bdt[1];
#pragma unroll
  for (int r = 0; r < 8; ++r) {
    const int rowblk = (r >> 2) * 64 + (r & 3) * 16;
#pragma unroll
    for (int j = 0; j < 4; ++j) {
      const int b = rowbase + rowblk + q4 + j;
      const long idx = (long)b * HDIM + h;
      const float dv = dtp[b];
      const float s1 = sigmoidf_(dv * wdt0 + bdt0);
      const float s2 = sigmoidf_(dv * wdt1 + bdt1);
      const float sbar = s1 * sigmoidf_(acc[r][0][j] + bi0);
      const float s = s2 * sigmoidf_(acc[r][1][j] + bi1);
      const float zt = tanhf_(acc[r][2][j] + bi2);
      const float iz = acc[r][3][j] + bi3;
      const float znew = (1.0f - s) * z[idx] + s * zt;
      out[(long)BATCH * HDIM + idx] = znew;  // z_new output (f32)
      out[idx] = iz;                          // park i_z in y_new slot
      znb[idx] = f2bf(znew);                  // bf16 operand for phase 2
      sbb[idx] = f2bf(sbar);
    }
  }
}

// ---- phase 2: z_new@Wz^T + y_new epilogue ----
__global__ __launch_bounds__(512, 2) void k_gemm2(
    const unsigned short* __restrict__ Zn, const unsigned short* __restrict__ Wzb,
    const unsigned short* __restrict__ sbb, const float* __restrict__ yin,
    const float* __restrict__ bz, float* __restrict__ out) {
  __shared__ char As[65536];
  __shared__ char Bs[65536];
  const int bid = blockIdx.x;
  const int sid = (bid & 7) * 32 + (bid >> 3);  // 256 % 8 == 0
  const int bm = sid >> 2, bn = sid & 3;
  f32x4 acc[8][4];
#pragma unroll
  for (int r = 0; r < 8; ++r)
#pragma unroll
    for (int n = 0; n < 4; ++n) acc[r][n] = (f32x4)(0.0f);

  gemm256<HDIM>(Zn, Wzb, (long)bm * 256, (long)bn * 256, As, Bs, acc);

  const int t = threadIdx.x, lane = t & 63, wv = t >> 6;
  const int wm = wv >> 2, wn = wv & 3;
  const int rA = lane & 15, q4 = (lane >> 4) << 2;
  const int rowbase = bm * 256 + wm * 128;
#pragma unroll
  for (int n = 0; n < 4; ++n) {
    const int hc = bn * 256 + wn * 64 + n * 16 + rA;
    const float bzv = bz[hc];
#pragma unroll
    for (int r = 0; r < 8; ++r) {
      const int rowblk = (r >> 2) * 64 + (r & 3) * 16;
#pragma unroll
      for (int j = 0; j < 4; ++j) {
        const int b = rowbase + rowblk + q4 + j;
        const long idx = (long)b * HDIM + hc;
        const float tv = tanhf_(acc[r][n][j] + bzv + out[idx]);  // out[idx] holds i_z
        const float sb = bf2f(sbb[idx]);
        out[idx] = (1.0f - sb) * yin[idx] + sb * tv;  // y_new (same addr, same thread)
      }
    }
  }
}

extern "C" void kernel_launch(void* const* d_in, const int* in_sizes, int n_in,
                              void* d_out, int out_size, void* d_ws, size_t ws_size,
                              hipStream_t stream) {
  const float* x   = (const float*)d_in[0];
  const float* y   = (const float*)d_in[1];
  const float* z   = (const float*)d_in[2];
  const float* dtp = (const float*)d_in[3];
  const float* Wih = (const float*)d_in[4];
  const float* bih = (const float*)d_in[5];
  const float* Whh = (const float*)d_in[6];
  const float* bhh = (const float*)d_in[7];
  const float* Wz  = (const float*)d_in[8];
  const float* bz  = (const float*)d_in[9];
  const float* Wdt = (const float*)d_in[10];
  const float* bdt = (const float*)d_in[11];

  char* ws = (char*)d_ws;
  unsigned short* U    = (unsigned short*)(ws);              // 67,108,864 B
  unsigned short* Wcat = (unsigned short*)(ws + 67108864);   // 16,777,216 B
  unsigned short* Wzb  = (unsigned short*)(ws + 83886080);   //  2,097,152 B
  unsigned short* Znb  = (unsigned short*)(ws + 85983232);   // 33,554,432 B
  unsigned short* Sbb  = (unsigned short*)(ws + 119537664);  // 33,554,432 B -> total 153,092,096 B
  float* out = (float*)d_out;

  k_convU<<<2048, 256, 0, stream>>>(x, y, U);
  k_convW<<<2048, 256, 0, stream>>>(Wih, Whh, Wz, Wcat, Wzb);
  k_gemm1<<<1024, 512, 0, stream>>>(U, Wcat, z, dtp, bih, bhh, Wdt, bdt, out, Znb, Sbb);
  k_gemm2<<<256, 512, 0, stream>>>(Znb, Wzb, Sbb, y, bz, out);
}